// Round 5
// baseline (861.068 us; speedup 1.0000x reference)
//
#include <hip/hip_runtime.h>
#include <hip/hip_bf16.h>

// GNN: 3x GCNConv (25->64->64->32) + global mean pool (256 graphs) + MLP head.
// Round 4: XCD-homed CSR placement. R3 showed 8 dst-range passes did NOT cut
// WRITE_SIZE (197MB for 25.6MB payload): pass blocks were spread across all 8
// XCDs, so each 64B ep line was partially dirtied in up to 8 non-coherent L2s
// -> per-XCD partial writebacks, no merging. Now pass = blockIdx.x % 8 on a
// 1-D grid: round-robin dispatch homes each pass (dst range) on ONE XCD, so
// an ep line is dirty in exactly one L2 and stores merge before writeback.
// Also: nontemporal streaming loads (src/dst in place, ep in gather) to keep
// the reused data (ep window / h rows) L2-resident.

#define IN_DIM 25
#define HID 64
#define OUT3 32

__device__ inline int ld_nt_i32(const int* p) {
    return __builtin_nontemporal_load(p);
}
__device__ inline float2 ld_nt_f2(const float2* p) {
    unsigned long long raw = __builtin_nontemporal_load((const unsigned long long*)p);
    float2 r;
    r.x = __uint_as_float((unsigned int)(raw & 0xffffffffull));
    r.y = __uint_as_float((unsigned int)(raw >> 32));
    return r;
}

// ---------------- CSR build ----------------
__global__ void hist_kernel(const int* __restrict__ dst, int* __restrict__ cnt, int nE) {
    int e = blockIdx.x * 256 + threadIdx.x;
    if (e < nE) atomicAdd(&cnt[dst[e]], 1);
}

__global__ void dinv_kernel(const int* __restrict__ cnt, float* __restrict__ dinv, int n) {
    int i = blockIdx.x * 256 + threadIdx.x;
    if (i < n) dinv[i] = rsqrtf((float)cnt[i] + 1.0f);   // + self loop
}

__global__ __launch_bounds__(256) void scan_reduce(const int* __restrict__ cnt,
                                                   int* __restrict__ bsums, int n) {
    __shared__ int sdata[256];
    int base = blockIdx.x * 2048 + threadIdx.x * 8;
    int s = 0;
#pragma unroll
    for (int j = 0; j < 8; ++j) { int i = base + j; if (i < n) s += cnt[i]; }
    sdata[threadIdx.x] = s;
    __syncthreads();
    for (int off = 128; off > 0; off >>= 1) {
        if (threadIdx.x < off) sdata[threadIdx.x] += sdata[threadIdx.x + off];
        __syncthreads();
    }
    if (threadIdx.x == 0) bsums[blockIdx.x] = sdata[0];
}

__global__ void scan_sums(int* __restrict__ bsums, int nb) {
    if (threadIdx.x == 0 && blockIdx.x == 0) {
        int acc = 0;
        for (int i = 0; i < nb; ++i) { int v = bsums[i]; bsums[i] = acc; acc += v; }
        bsums[nb] = acc;
    }
}

__global__ __launch_bounds__(256) void scan_write(const int* __restrict__ cnt,
                                                  const int* __restrict__ bsums,
                                                  int* __restrict__ row_ptr,
                                                  int* __restrict__ rpc, int n, int nb) {
    __shared__ int sdata[256];
    int t = threadIdx.x;
    int base = blockIdx.x * 2048 + t * 8;
    int loc[8];
    int s = 0;
#pragma unroll
    for (int j = 0; j < 8; ++j) {
        int i = base + j;
        int v = (i < n) ? cnt[i] : 0;
        loc[j] = s; s += v;
    }
    sdata[t] = s;
    __syncthreads();
    for (int off = 1; off < 256; off <<= 1) {
        int mine = sdata[t];
        int add  = (t >= off) ? sdata[t - off] : 0;
        __syncthreads();
        sdata[t] = mine + add;
        __syncthreads();
    }
    int excl = sdata[t] - s + bsums[blockIdx.x];
#pragma unroll
    for (int j = 0; j < 8; ++j) {
        int i = base + j;
        if (i < n) { row_ptr[i] = excl + loc[j]; rpc[i] = excl + loc[j]; }
    }
    if (blockIdx.x == 0 && t == 0) row_ptr[n] = bsums[nb];
}

// XCD-homed placement: pass = blockIdx.x % 8 lands on XCD (pass) under
// round-robin dispatch; each pass owns one dst range, so each ep cache line
// is dirtied by exactly one XCD's L2 and stores merge before writeback.
// Each block covers 1024 edges (4 per thread, coalesced).
__global__ __launch_bounds__(256) void place_kernel(
        const int* __restrict__ src, const int* __restrict__ dst,
        const float* __restrict__ dinv, int* __restrict__ rpc,
        float2* __restrict__ ep, int nE, int chunkN) {
    int pass = blockIdx.x & 7;
    int blk  = blockIdx.x >> 3;
    int lo = pass * chunkN;
    int hi = lo + chunkN;
    int base = blk * 1024 + threadIdx.x;
#pragma unroll
    for (int j = 0; j < 4; ++j) {
        int e = base + j * 256;
        if (e < nE) {
            int d = ld_nt_i32(&dst[e]);
            if (d >= lo && d < hi) {
                int s = ld_nt_i32(&src[e]);
                int pos = atomicAdd(&rpc[d], 1);
                float2 p;
                p.x = __int_as_float(s);
                p.y = dinv[s] * dinv[d];
                ep[pos] = p;
            }
        }
    }
}

// ---------------- pad helpers ----------------
__global__ void padx_kernel(const float* __restrict__ x, float* __restrict__ xp, int n) {
    int i = blockIdx.x * 256 + threadIdx.x;
    if (i < n * 32) {
        int node = i >> 5, c = i & 31;
        xp[i] = (c < IN_DIM) ? x[(size_t)node * IN_DIM + c] : 0.f;
    }
}

__global__ void padw_kernel(const float* __restrict__ W1, float* __restrict__ W1p) {
    int i = blockIdx.x * 256 + threadIdx.x;
    if (i < 32 * HID) {
        int r = i >> 6, c = i & 63;
        W1p[i] = (r < IN_DIM) ? W1[r * HID + c] : 0.f;
    }
}

// ---------------- dense layer: out = in @ W [+ bias, relu] ----------------
template<int INF, int OUTF, bool ACT>
__global__ __launch_bounds__(256) void gemm_kernel(
        const float* __restrict__ in, const float* __restrict__ W,
        const float* __restrict__ bias, float* __restrict__ out, int n) {
    constexpr int TPN = OUTF / 4;
    constexpr int NPB = 256 / TPN;
    constexpr int LDK = INF + 4;
    __shared__ float sW[INF * OUTF];
    __shared__ float sIn[NPB][LDK];
    for (int i = threadIdx.x; i < INF * OUTF; i += 256) sW[i] = W[i];
    int node0 = blockIdx.x * NPB;
    for (int i = threadIdx.x; i < NPB * INF; i += 256) {
        int ln = i / INF, k = i % INF;
        int node = node0 + ln;
        sIn[ln][k] = (node < n) ? in[(size_t)node * INF + k] : 0.f;
    }
    __syncthreads();
    int g   = threadIdx.x / TPN;
    int of0 = (threadIdx.x % TPN) * 4;
    int node = node0 + g;
    float4 acc = make_float4(0.f, 0.f, 0.f, 0.f);
#pragma unroll
    for (int k = 0; k < INF; ++k) {
        float aj = sIn[g][k];
        const float4 wv = *(const float4*)&sW[k * OUTF + of0];
        acc.x += aj * wv.x; acc.y += aj * wv.y;
        acc.z += aj * wv.z; acc.w += aj * wv.w;
    }
    if (ACT) {
        const float4 bv = *(const float4*)&bias[of0];
        acc.x = fmaxf(acc.x + bv.x, 0.f);
        acc.y = fmaxf(acc.y + bv.y, 0.f);
        acc.z = fmaxf(acc.z + bv.z, 0.f);
        acc.w = fmaxf(acc.w + bv.w, 0.f);
    }
    if (node < n) *(float4*)&out[(size_t)node * OUTF + of0] = acc;
}

// ---------------- CSR gather aggregation [+ fused relu(acc + bias)] --------
// ep streamed with nontemporal loads so the reused h rows keep L2.
template<int F, bool ACT>
__global__ __launch_bounds__(256) void gather_kernel(
        const float* __restrict__ h, const float* __restrict__ dinv,
        const int* __restrict__ row_ptr, const float2* __restrict__ ep,
        const float* __restrict__ bias, float* __restrict__ agg, int n) {
    constexpr int NPW = 64 / F;
    int wid  = (blockIdx.x * 256 + threadIdx.x) >> 6;
    int lane = threadIdx.x & 63;
    int sub  = lane / F;
    int f    = lane % F;
    int node = wid * NPW + sub;
    if (node >= n) return;
    float dv = dinv[node];
    float acc = h[(size_t)node * F + f] * dv * dv;   // self loop
    int e = row_ptr[node], end = row_ptr[node + 1];
    for (; e + 8 <= end; e += 8) {
        float2 p[8];
        float  v[8];
#pragma unroll
        for (int j = 0; j < 8; ++j) p[j] = ld_nt_f2(&ep[e + j]);
#pragma unroll
        for (int j = 0; j < 8; ++j) v[j] = h[(size_t)__float_as_int(p[j].x) * F + f];
#pragma unroll
        for (int j = 0; j < 8; ++j) acc += v[j] * p[j].y;
    }
    for (; e + 2 <= end; e += 2) {
        float2 p0 = ld_nt_f2(&ep[e]), p1 = ld_nt_f2(&ep[e + 1]);
        float v0 = h[(size_t)__float_as_int(p0.x) * F + f];
        float v1 = h[(size_t)__float_as_int(p1.x) * F + f];
        acc += v0 * p0.y + v1 * p1.y;
    }
    if (e < end) {
        float2 p = ld_nt_f2(&ep[e]);
        acc += h[(size_t)__float_as_int(p.x) * F + f] * p.y;
    }
    float r = ACT ? fmaxf(acc + bias[f], 0.f) : acc;
    agg[(size_t)node * F + f] = r;
}

// ---------------- mean pool: block per graph (batch sorted; input activated) ----
__global__ __launch_bounds__(256) void pool_kernel(
        const float* __restrict__ h3, const int* __restrict__ batch,
        int n, float* __restrict__ pool) {
    int g = blockIdx.x;
    int lo = 0, hi = n;
    while (lo < hi) { int m = (lo + hi) >> 1; if (batch[m] < g) lo = m + 1; else hi = m; }
    int s = lo;
    hi = n;
    while (lo < hi) { int m = (lo + hi) >> 1; if (batch[m] < g + 1) lo = m + 1; else hi = m; }
    int e = lo;
    constexpr int F = OUT3;
    int ln = threadIdx.x / F;
    int f  = threadIdx.x % F;
    float acc = 0.f;
    for (int i = s + ln; i < e; i += 8)
        acc += h3[(size_t)i * F + f];
    __shared__ float red[8][F];
    red[ln][f] = acc;
    __syncthreads();
    if (ln == 0) {
        float t = 0.f;
#pragma unroll
        for (int j = 0; j < 8; ++j) t += red[j][f];
        float cnt = (float)((e - s) > 0 ? (e - s) : 1);
        pool[g * F + f] = t / cnt;
    }
}

// ---------------- head ----------------
__global__ __launch_bounds__(256) void head_kernel(
        const float* __restrict__ pool, const float* __restrict__ Wh1,
        const float* __restrict__ bh1, const float* __restrict__ Wh2,
        const float* __restrict__ bh2, float* __restrict__ out) {
    __shared__ float sW1[32 * 32];
    __shared__ float sb1[32];
    __shared__ float sW2[32];
    int t = threadIdx.x;
    for (int i = t; i < 1024; i += 256) sW1[i] = Wh1[i];
    if (t < 32) { sb1[t] = bh1[t]; sW2[t] = Wh2[t]; }
    __syncthreads();
    int g = t;
    float y = bh2[0];
    const float* p = &pool[g * 32];
#pragma unroll 4
    for (int j = 0; j < 32; ++j) {
        float a = sb1[j];
#pragma unroll
        for (int k = 0; k < 32; ++k) a += p[k] * sW1[k * 32 + j];
        y += fmaxf(a, 0.f) * sW2[j];
    }
    out[g] = y;
}

extern "C" void kernel_launch(void* const* d_in, const int* in_sizes, int n_in,
                              void* d_out, int out_size, void* d_ws, size_t ws_size,
                              hipStream_t stream) {
    const float* x    = (const float*)d_in[0];
    const int*   ei   = (const int*)  d_in[1];
    const int*   batch= (const int*)  d_in[2];
    const float* W1   = (const float*)d_in[3];
    const float* b1   = (const float*)d_in[4];
    const float* W2   = (const float*)d_in[5];
    const float* b2   = (const float*)d_in[6];
    const float* W3   = (const float*)d_in[7];
    const float* b3   = (const float*)d_in[8];
    const float* Wh1  = (const float*)d_in[9];
    const float* bh1  = (const float*)d_in[10];
    const float* Wh2  = (const float*)d_in[11];
    const float* bh2  = (const float*)d_in[12];
    float* out = (float*)d_out;

    const int N = in_sizes[0] / IN_DIM;
    const int E = in_sizes[1] / 2;
    const int* src = ei;
    const int* dst = ei + E;
    const int NB_SCAN = (N + 2047) / 2048;

    // workspace layout
    char* base = (char*)d_ws;
    float2* ep     = (float2*)base;                 base += (size_t)E * 8;
    int*   cnt     = (int*)base;                    base += (size_t)N * 4;
    int*   row_ptr = (int*)base;                    base += (size_t)(N + 1) * 4;
    int*   rpc     = (int*)base;                    base += (size_t)N * 4;
    int*   bsums   = (int*)base;                    base += (size_t)(NB_SCAN + 8) * 4;
    float* dinv    = (float*)base;                  base += (size_t)N * 4;
    float* W1p     = (float*)base;                  base += (size_t)32 * HID * 4;
    float* bufA    = (float*)base;                  base += (size_t)N * HID * 4;
    float* bufB    = (float*)base;                  base += (size_t)N * HID * 4;
    float* pool    = (float*)base;

    // ---- CSR build ----
    hipMemsetAsync(cnt, 0, (size_t)N * sizeof(int), stream);
    hist_kernel<<<(E + 255) / 256, 256, 0, stream>>>(dst, cnt, E);
    dinv_kernel<<<(N + 255) / 256, 256, 0, stream>>>(cnt, dinv, N);
    scan_reduce<<<NB_SCAN, 256, 0, stream>>>(cnt, bsums, N);
    scan_sums<<<1, 64, 0, stream>>>(bsums, NB_SCAN);
    scan_write<<<NB_SCAN, 256, 0, stream>>>(cnt, bsums, row_ptr, rpc, N, NB_SCAN);
    {
        const int chunkN = (N + 7) / 8;
        const int bpp = (E + 1023) / 1024;     // blocks per pass
        place_kernel<<<bpp * 8, 256, 0, stream>>>(src, dst, dinv, rpc, ep, E, chunkN);
    }

    // ---- layer 1 (reordered): aggX = A_hat Xp ; h1 = relu(aggX @ W1p + b1) ----
    padx_kernel<<<((size_t)N * 32 + 255) / 256, 256, 0, stream>>>(x, bufB, N);
    padw_kernel<<<(32 * HID + 255) / 256, 256, 0, stream>>>(W1, W1p);
    gather_kernel<32, false><<<(N + 7) / 8, 256, 0, stream>>>(bufB, dinv, row_ptr, ep, nullptr, bufA, N);
    gemm_kernel<32, HID, true><<<(N + 15) / 16, 256, 0, stream>>>(bufA, W1p, b1, bufB, N);

    // ---- layer 2: t2 = h1 @ W2 ; h2 = relu(A_hat t2 + b2) ----
    gemm_kernel<HID, HID, false><<<(N + 15) / 16, 256, 0, stream>>>(bufB, W2, nullptr, bufA, N);
    gather_kernel<HID, true><<<(N + 3) / 4, 256, 0, stream>>>(bufA, dinv, row_ptr, ep, b2, bufB, N);

    // ---- layer 3: t3 = h2 @ W3 ; h3 = relu(A_hat t3 + b3) ----
    gemm_kernel<HID, OUT3, false><<<(N + 31) / 32, 256, 0, stream>>>(bufB, W3, nullptr, bufA, N);
    gather_kernel<OUT3, true><<<(N + 7) / 8, 256, 0, stream>>>(bufA, dinv, row_ptr, ep, b3, bufB, N);

    // ---- pool + head ----
    pool_kernel<<<256, 256, 0, stream>>>(bufB, batch, N, pool);
    head_kernel<<<1, 256, 0, stream>>>(pool, Wh1, bh1, Wh2, bh2, out);
}

// Round 6
// 629.930 us; speedup vs baseline: 1.3669x; 1.3669x over previous
//
#include <hip/hip_runtime.h>
#include <hip/hip_bf16.h>

// GNN: 3x GCNConv (25->64->64->32) + global mean pool (256 graphs) + MLP head.
// Round 5: coalesced CSR build. R3/R4 proved random 8B CSR stores can't be
// write-combined by scheduling (WRITE_SIZE stuck ~180-200MB for 25.6MB of
// payload). New build: two-level counting sort with ALL global writes
// sequential: (1) partition edges into 782 buckets of 128 dst nodes (LDS
// local sort -> coalesced run writes, 4B packed payload (dlow<<17|src)),
// (2) per-bucket LDS counting sort -> in-place coalesced writeback, emitting
// row_ptr + dinv (degree = in-bucket count) on the way. Deletes the 3.2M
// global atomic histogram and the 100K-node scan chain. Gather reads a 4B
// col stream + dinv[col] (L2-resident, wave-broadcast).
// Assumes N < 2^17 (N=100000) for the 17-bit src packing.

#define IN_DIM 25
#define HID 64
#define OUT3 32
#define BK_LOG 7
#define BK_NODES 128          // nodes per bucket
#define MAXB 1024             // max buckets supported (N <= 131072)
#define EPB1 16384            // edges per partition block
#define BCAP 8192             // bucket capacity (avg 4096, sigma ~64)

__device__ inline int ld_nt_i32(const int* p) {
    return __builtin_nontemporal_load(p);
}

// ---------------- stage 1: bucket histogram (LDS-privatized) ----------------
__global__ __launch_bounds__(256) void bucket_hist(const int* __restrict__ dst,
                                                   int* __restrict__ bhist, int nE) {
    __shared__ int h[MAXB];
    for (int i = threadIdx.x; i < MAXB; i += 256) h[i] = 0;
    __syncthreads();
    int e0 = blockIdx.x * 8192;
    int cnt = min(8192, nE - e0);
    for (int i = threadIdx.x; i < cnt; i += 256)
        atomicAdd(&h[(unsigned)dst[e0 + i] >> BK_LOG], 1);
    __syncthreads();
    for (int i = threadIdx.x; i < MAXB; i += 256)
        if (h[i]) atomicAdd(&bhist[i], h[i]);
}

// ---------------- stage 2: scan 782 bucket counts (1 block) ----------------
__global__ __launch_bounds__(256) void bucket_scan(const int* __restrict__ bhist,
                                                   int* __restrict__ bbase,
                                                   int* __restrict__ cursor,
                                                   int* __restrict__ row_ptr,
                                                   int nb, int nE, int nN) {
    __shared__ int s4[256];
    int t = threadIdx.x;
    int v[4]; int sum = 0;
#pragma unroll
    for (int j = 0; j < 4; ++j) {
        int b = 4 * t + j;
        v[j] = (b < nb) ? bhist[b] : 0;
        sum += v[j];
    }
    s4[t] = sum;
    __syncthreads();
    for (int off = 1; off < 256; off <<= 1) {
        int mine = s4[t];
        int add = (t >= off) ? s4[t - off] : 0;
        __syncthreads();
        s4[t] = mine + add;
        __syncthreads();
    }
    int run = s4[t] - sum;   // exclusive prefix of this thread's 4 buckets
#pragma unroll
    for (int j = 0; j < 4; ++j) {
        int b = 4 * t + j;
        if (b < nb) { bbase[b] = run; cursor[b] = run; }
        run += v[j];
    }
    if (t == 0) { bbase[nb] = nE; row_ptr[nN] = nE; }
}

// ---------------- stage 3: partition edges into buckets (coalesced) --------
// Per block: local hist -> local scan -> reserve global runs (1 atomic per
// bucket per block) -> LDS bucket-sort -> sequential sweep out (packed 4B).
__global__ __launch_bounds__(256) void partition_kernel(
        const int* __restrict__ src, const int* __restrict__ dst,
        int* __restrict__ cursor, unsigned int* __restrict__ ebuf, int nE) {
    __shared__ int lh[MAXB];              // hist, then local excl scan
    __shared__ int lrun[MAXB];            // global run base
    __shared__ int lcur[MAXB];            // local fill cursor
    __shared__ int swp[256];
    __shared__ unsigned int stg[EPB1];    // bucket-sorted packed words (64KB)
    __shared__ unsigned short sbk[EPB1];  // bucket id per sorted slot (32KB)
    int t = threadIdx.x;
    int e0 = blockIdx.x * EPB1;
    int cnt = min(EPB1, nE - e0);
    for (int i = t; i < MAXB; i += 256) lh[i] = 0;
    __syncthreads();
    // Phase A: local bucket histogram
    for (int i = t; i < cnt; i += 256)
        atomicAdd(&lh[(unsigned)dst[e0 + i] >> BK_LOG], 1);
    __syncthreads();
    // local scan over MAXB (4 buckets/thread) + global run reservation
    int v[4]; int sum = 0;
#pragma unroll
    for (int j = 0; j < 4; ++j) { v[j] = lh[4 * t + j]; sum += v[j]; }
    swp[t] = sum;
    __syncthreads();
    for (int off = 1; off < 256; off <<= 1) {
        int mine = swp[t];
        int add = (t >= off) ? swp[t - off] : 0;
        __syncthreads();
        swp[t] = mine + add;
        __syncthreads();
    }
    int run = swp[t] - sum;
#pragma unroll
    for (int j = 0; j < 4; ++j) {
        int b = 4 * t + j;
        lh[b] = run;                 // local exclusive scan
        lcur[b] = 0;
        if (v[j] > 0) lrun[b] = atomicAdd(&cursor[b], v[j]);
        run += v[j];
    }
    __syncthreads();
    // Phase B: place into LDS sorted order (dst/src re-read: L2-hot 64KB)
    for (int i = t; i < cnt; i += 256) {
        int d = dst[e0 + i];
        int s = src[e0 + i];
        int b = (unsigned)d >> BK_LOG;
        int lp = atomicAdd(&lcur[b], 1);
        int slot = lh[b] + lp;
        stg[slot] = ((unsigned)(d & (BK_NODES - 1)) << 17) | (unsigned)s;
        sbk[slot] = (unsigned short)b;
    }
    __syncthreads();
    // Phase C: sequential sweep -> coalesced run writes
    for (int i = t; i < cnt; i += 256) {
        int b = sbk[i];
        int g = lrun[b] + (i - lh[b]);
        ebuf[g] = stg[i];
    }
}

// ---------------- stage 4: per-bucket CSR sort + row_ptr + dinv ------------
__global__ __launch_bounds__(256) void bucket_csr_kernel(
        unsigned int* __restrict__ ebuf, const int* __restrict__ bbase,
        float* __restrict__ dinv, int* __restrict__ row_ptr, int nN) {
    int b = blockIdx.x;
    int node_lo = b << BK_LOG;
    int nn = min(BK_NODES, nN - node_lo);
    int base = bbase[b];
    int cnt = bbase[b + 1] - base;
    if (cnt > BCAP) cnt = BCAP;   // statistically impossible; memory guard
    __shared__ unsigned int in[BCAP];    // 32KB
    __shared__ unsigned int outb[BCAP];  // 32KB
    __shared__ int h[BK_NODES], sc[BK_NODES], lc[BK_NODES];
    int t = threadIdx.x;
    for (int i = t; i < cnt; i += 256) in[i] = ebuf[base + i];
    if (t < BK_NODES) { h[t] = 0; lc[t] = 0; }
    __syncthreads();
    for (int i = t; i < cnt; i += 256) atomicAdd(&h[in[i] >> 17], 1);
    __syncthreads();
    if (t < BK_NODES) sc[t] = h[t];
    __syncthreads();
    for (int off = 1; off < BK_NODES; off <<= 1) {
        int val = 0;
        if (t < BK_NODES) { val = sc[t]; if (t >= off) val += sc[t - off]; }
        __syncthreads();
        if (t < BK_NODES) sc[t] = val;   // inclusive scan
        __syncthreads();
    }
    if (t < BK_NODES && t < nn) {
        dinv[node_lo + t] = rsqrtf((float)h[t] + 1.0f);       // + self loop
        row_ptr[node_lo + t] = base + (sc[t] - h[t]);
    }
    __syncthreads();
    for (int i = t; i < cnt; i += 256) {
        unsigned int w = in[i];
        int dl = w >> 17;
        int lp = atomicAdd(&lc[dl], 1);
        outb[(sc[dl] - h[dl]) + lp] = w & 0x1FFFFu;   // pure src index
    }
    __syncthreads();
    for (int i = t; i < cnt; i += 256) ebuf[base + i] = outb[i];  // coalesced
}

// ---------------- pad helpers ----------------
__global__ void padx_kernel(const float* __restrict__ x, float* __restrict__ xp, int n) {
    int i = blockIdx.x * 256 + threadIdx.x;
    if (i < n * 32) {
        int node = i >> 5, c = i & 31;
        xp[i] = (c < IN_DIM) ? x[(size_t)node * IN_DIM + c] : 0.f;
    }
}

__global__ void padw_kernel(const float* __restrict__ W1, float* __restrict__ W1p) {
    int i = blockIdx.x * 256 + threadIdx.x;
    if (i < 32 * HID) {
        int r = i >> 6, c = i & 63;
        W1p[i] = (r < IN_DIM) ? W1[r * HID + c] : 0.f;
    }
}

// ---------------- dense layer: out = in @ W [+ bias, relu] ----------------
template<int INF, int OUTF, bool ACT>
__global__ __launch_bounds__(256) void gemm_kernel(
        const float* __restrict__ in, const float* __restrict__ W,
        const float* __restrict__ bias, float* __restrict__ out, int n) {
    constexpr int TPN = OUTF / 4;
    constexpr int NPB = 256 / TPN;
    constexpr int LDK = INF + 4;
    __shared__ float sW[INF * OUTF];
    __shared__ float sIn[NPB][LDK];
    for (int i = threadIdx.x; i < INF * OUTF; i += 256) sW[i] = W[i];
    int node0 = blockIdx.x * NPB;
    for (int i = threadIdx.x; i < NPB * INF; i += 256) {
        int ln = i / INF, k = i % INF;
        int node = node0 + ln;
        sIn[ln][k] = (node < n) ? in[(size_t)node * INF + k] : 0.f;
    }
    __syncthreads();
    int g   = threadIdx.x / TPN;
    int of0 = (threadIdx.x % TPN) * 4;
    int node = node0 + g;
    float4 acc = make_float4(0.f, 0.f, 0.f, 0.f);
#pragma unroll
    for (int k = 0; k < INF; ++k) {
        float aj = sIn[g][k];
        const float4 wv = *(const float4*)&sW[k * OUTF + of0];
        acc.x += aj * wv.x; acc.y += aj * wv.y;
        acc.z += aj * wv.z; acc.w += aj * wv.w;
    }
    if (ACT) {
        const float4 bv = *(const float4*)&bias[of0];
        acc.x = fmaxf(acc.x + bv.x, 0.f);
        acc.y = fmaxf(acc.y + bv.y, 0.f);
        acc.z = fmaxf(acc.z + bv.z, 0.f);
        acc.w = fmaxf(acc.w + bv.w, 0.f);
    }
    if (node < n) *(float4*)&out[(size_t)node * OUTF + of0] = acc;
}

// ---------------- CSR gather aggregation [+ fused relu(acc + bias)] --------
// col = 4B src stream (nt loads); w computed as dinv[s]*dinv[d] with
// dinv[d] factored out of the loop. dinv is 400KB -> L2-resident.
template<int F, bool ACT>
__global__ __launch_bounds__(256) void gather_kernel(
        const float* __restrict__ h, const float* __restrict__ dinv,
        const int* __restrict__ row_ptr, const int* __restrict__ col,
        const float* __restrict__ bias, float* __restrict__ agg, int n) {
    constexpr int NPW = 64 / F;
    int wid  = (blockIdx.x * 256 + threadIdx.x) >> 6;
    int lane = threadIdx.x & 63;
    int sub  = lane / F;
    int f    = lane % F;
    int node = wid * NPW + sub;
    if (node >= n) return;
    float dvd = dinv[node];
    float acc = h[(size_t)node * F + f] * dvd;   // self loop (x dvd again later)
    int e = row_ptr[node], end = row_ptr[node + 1];
    for (; e + 8 <= end; e += 8) {
        int   c[8];
        float dv[8], v[8];
#pragma unroll
        for (int j = 0; j < 8; ++j) c[j] = ld_nt_i32(&col[e + j]);
#pragma unroll
        for (int j = 0; j < 8; ++j) dv[j] = dinv[c[j]];
#pragma unroll
        for (int j = 0; j < 8; ++j) v[j] = h[(size_t)c[j] * F + f];
#pragma unroll
        for (int j = 0; j < 8; ++j) acc += v[j] * dv[j];
    }
    for (; e + 2 <= end; e += 2) {
        int c0 = ld_nt_i32(&col[e]), c1 = ld_nt_i32(&col[e + 1]);
        acc += h[(size_t)c0 * F + f] * dinv[c0] + h[(size_t)c1 * F + f] * dinv[c1];
    }
    if (e < end) {
        int c0 = ld_nt_i32(&col[e]);
        acc += h[(size_t)c0 * F + f] * dinv[c0];
    }
    acc *= dvd;
    float r = ACT ? fmaxf(acc + bias[f], 0.f) : acc;
    agg[(size_t)node * F + f] = r;
}

// ---------------- mean pool: block per graph (batch sorted) ----------------
__global__ __launch_bounds__(256) void pool_kernel(
        const float* __restrict__ h3, const int* __restrict__ batch,
        int n, float* __restrict__ pool) {
    int g = blockIdx.x;
    int lo = 0, hi = n;
    while (lo < hi) { int m = (lo + hi) >> 1; if (batch[m] < g) lo = m + 1; else hi = m; }
    int s = lo;
    hi = n;
    while (lo < hi) { int m = (lo + hi) >> 1; if (batch[m] < g + 1) lo = m + 1; else hi = m; }
    int e = lo;
    constexpr int F = OUT3;
    int ln = threadIdx.x / F;
    int f  = threadIdx.x % F;
    float acc = 0.f;
    for (int i = s + ln; i < e; i += 8)
        acc += h3[(size_t)i * F + f];
    __shared__ float red[8][F];
    red[ln][f] = acc;
    __syncthreads();
    if (ln == 0) {
        float t = 0.f;
#pragma unroll
        for (int j = 0; j < 8; ++j) t += red[j][f];
        float cnt = (float)((e - s) > 0 ? (e - s) : 1);
        pool[g * F + f] = t / cnt;
    }
}

// ---------------- head ----------------
__global__ __launch_bounds__(256) void head_kernel(
        const float* __restrict__ pool, const float* __restrict__ Wh1,
        const float* __restrict__ bh1, const float* __restrict__ Wh2,
        const float* __restrict__ bh2, float* __restrict__ out) {
    __shared__ float sW1[32 * 32];
    __shared__ float sb1[32];
    __shared__ float sW2[32];
    int t = threadIdx.x;
    for (int i = t; i < 1024; i += 256) sW1[i] = Wh1[i];
    if (t < 32) { sb1[t] = bh1[t]; sW2[t] = Wh2[t]; }
    __syncthreads();
    int g = t;
    float y = bh2[0];
    const float* p = &pool[g * 32];
#pragma unroll 4
    for (int j = 0; j < 32; ++j) {
        float a = sb1[j];
#pragma unroll
        for (int k = 0; k < 32; ++k) a += p[k] * sW1[k * 32 + j];
        y += fmaxf(a, 0.f) * sW2[j];
    }
    out[g] = y;
}

extern "C" void kernel_launch(void* const* d_in, const int* in_sizes, int n_in,
                              void* d_out, int out_size, void* d_ws, size_t ws_size,
                              hipStream_t stream) {
    const float* x    = (const float*)d_in[0];
    const int*   ei   = (const int*)  d_in[1];
    const int*   batch= (const int*)  d_in[2];
    const float* W1   = (const float*)d_in[3];
    const float* b1   = (const float*)d_in[4];
    const float* W2   = (const float*)d_in[5];
    const float* b2   = (const float*)d_in[6];
    const float* W3   = (const float*)d_in[7];
    const float* b3   = (const float*)d_in[8];
    const float* Wh1  = (const float*)d_in[9];
    const float* bh1  = (const float*)d_in[10];
    const float* Wh2  = (const float*)d_in[11];
    const float* bh2  = (const float*)d_in[12];
    float* out = (float*)d_out;

    const int N = in_sizes[0] / IN_DIM;
    const int E = in_sizes[1] / 2;
    const int* src = ei;
    const int* dst = ei + E;
    const int NB = (N + BK_NODES - 1) >> BK_LOG;   // 782 buckets

    // workspace layout (all 4B elements)
    char* base = (char*)d_ws;
    unsigned int* ebuf = (unsigned int*)base;       base += (size_t)E * 4;
    int*   bhist   = (int*)base;                    base += (size_t)MAXB * 4;
    int*   bbase   = (int*)base;                    base += (size_t)(MAXB + 1) * 4;
    int*   cursor  = (int*)base;                    base += (size_t)MAXB * 4;
    int*   row_ptr = (int*)base;                    base += (size_t)(N + 1) * 4;
    float* dinv    = (float*)base;                  base += (size_t)N * 4;
    float* W1p     = (float*)base;                  base += (size_t)32 * HID * 4;
    float* bufA    = (float*)base;                  base += (size_t)N * HID * 4;
    float* bufB    = (float*)base;                  base += (size_t)N * HID * 4;
    float* pool    = (float*)base;

    // ---- CSR build (coalesced counting sort) ----
    hipMemsetAsync(bhist, 0, (size_t)MAXB * sizeof(int), stream);
    bucket_hist<<<(E + 8191) / 8192, 256, 0, stream>>>(dst, bhist, E);
    bucket_scan<<<1, 256, 0, stream>>>(bhist, bbase, cursor, row_ptr, NB, E, N);
    partition_kernel<<<(E + EPB1 - 1) / EPB1, 256, 0, stream>>>(src, dst, cursor, ebuf, E);
    bucket_csr_kernel<<<NB, 256, 0, stream>>>(ebuf, bbase, dinv, row_ptr, N);
    const int* col = (const int*)ebuf;

    // ---- layer 1 (reordered): aggX = A_hat Xp ; h1 = relu(aggX @ W1p + b1) ----
    padx_kernel<<<((size_t)N * 32 + 255) / 256, 256, 0, stream>>>(x, bufB, N);
    padw_kernel<<<(32 * HID + 255) / 256, 256, 0, stream>>>(W1, W1p);
    gather_kernel<32, false><<<(N + 7) / 8, 256, 0, stream>>>(bufB, dinv, row_ptr, col, nullptr, bufA, N);
    gemm_kernel<32, HID, true><<<(N + 15) / 16, 256, 0, stream>>>(bufA, W1p, b1, bufB, N);

    // ---- layer 2: t2 = h1 @ W2 ; h2 = relu(A_hat t2 + b2) ----
    gemm_kernel<HID, HID, false><<<(N + 15) / 16, 256, 0, stream>>>(bufB, W2, nullptr, bufA, N);
    gather_kernel<HID, true><<<(N + 3) / 4, 256, 0, stream>>>(bufA, dinv, row_ptr, col, b2, bufB, N);

    // ---- layer 3: t3 = h2 @ W3 ; h3 = relu(A_hat t3 + b3) ----
    gemm_kernel<HID, OUT3, false><<<(N + 31) / 32, 256, 0, stream>>>(bufB, W3, nullptr, bufA, N);
    gather_kernel<OUT3, true><<<(N + 7) / 8, 256, 0, stream>>>(bufA, dinv, row_ptr, col, b3, bufB, N);

    // ---- pool + head ----
    pool_kernel<<<256, 256, 0, stream>>>(bufB, batch, N, pool);
    head_kernel<<<1, 256, 0, stream>>>(pool, Wh1, bh1, Wh2, bh2, out);
}

// Round 7
// 613.997 us; speedup vs baseline: 1.4024x; 1.0260x over previous
//
#include <hip/hip_runtime.h>
#include <hip/hip_bf16.h>

// GNN: 3x GCNConv (25->64->64->32) + global mean pool (256 graphs) + MLP head.
// Round 6: pre-scaled gather. dinv[src] is folded into the producer
// (GEMM epilogue / padx), so the gather inner loop is col-load -> h-load ->
// add: no per-edge random dinv load, no per-edge multiply, shorter dep
// chain. Unroll 16 with 4 accumulators for 2x outstanding random loads.
// CSR build: two-level counting sort (R5) -- all global writes coalesced.
// Assumes N < 2^17 (N=100000) for the 17-bit src packing.

#define IN_DIM 25
#define HID 64
#define OUT3 32
#define BK_LOG 7
#define BK_NODES 128
#define MAXB 1024
#define EPB1 16384
#define BCAP 8192

__device__ inline int ld_nt_i32(const int* p) {
    return __builtin_nontemporal_load(p);
}

// ---------------- stage 1: bucket histogram (LDS-privatized) ----------------
__global__ __launch_bounds__(256) void bucket_hist(const int* __restrict__ dst,
                                                   int* __restrict__ bhist, int nE) {
    __shared__ int h[MAXB];
    for (int i = threadIdx.x; i < MAXB; i += 256) h[i] = 0;
    __syncthreads();
    int e0 = blockIdx.x * 8192;
    int cnt = min(8192, nE - e0);
    for (int i = threadIdx.x; i < cnt; i += 256)
        atomicAdd(&h[(unsigned)dst[e0 + i] >> BK_LOG], 1);
    __syncthreads();
    for (int i = threadIdx.x; i < MAXB; i += 256)
        if (h[i]) atomicAdd(&bhist[i], h[i]);
}

// ---------------- stage 2: scan bucket counts (1 block) ----------------
__global__ __launch_bounds__(256) void bucket_scan(const int* __restrict__ bhist,
                                                   int* __restrict__ bbase,
                                                   int* __restrict__ cursor,
                                                   int* __restrict__ row_ptr,
                                                   int nb, int nE, int nN) {
    __shared__ int s4[256];
    int t = threadIdx.x;
    int v[4]; int sum = 0;
#pragma unroll
    for (int j = 0; j < 4; ++j) {
        int b = 4 * t + j;
        v[j] = (b < nb) ? bhist[b] : 0;
        sum += v[j];
    }
    s4[t] = sum;
    __syncthreads();
    for (int off = 1; off < 256; off <<= 1) {
        int mine = s4[t];
        int add = (t >= off) ? s4[t - off] : 0;
        __syncthreads();
        s4[t] = mine + add;
        __syncthreads();
    }
    int run = s4[t] - sum;
#pragma unroll
    for (int j = 0; j < 4; ++j) {
        int b = 4 * t + j;
        if (b < nb) { bbase[b] = run; cursor[b] = run; }
        run += v[j];
    }
    if (t == 0) { bbase[nb] = nE; row_ptr[nN] = nE; }
}

// ---------------- stage 3: partition edges into buckets (coalesced) --------
__global__ __launch_bounds__(256) void partition_kernel(
        const int* __restrict__ src, const int* __restrict__ dst,
        int* __restrict__ cursor, unsigned int* __restrict__ ebuf, int nE) {
    __shared__ int lh[MAXB];
    __shared__ int lrun[MAXB];
    __shared__ int lcur[MAXB];
    __shared__ int swp[256];
    __shared__ unsigned int stg[EPB1];
    __shared__ unsigned short sbk[EPB1];
    int t = threadIdx.x;
    int e0 = blockIdx.x * EPB1;
    int cnt = min(EPB1, nE - e0);
    for (int i = t; i < MAXB; i += 256) lh[i] = 0;
    __syncthreads();
    for (int i = t; i < cnt; i += 256)
        atomicAdd(&lh[(unsigned)dst[e0 + i] >> BK_LOG], 1);
    __syncthreads();
    int v[4]; int sum = 0;
#pragma unroll
    for (int j = 0; j < 4; ++j) { v[j] = lh[4 * t + j]; sum += v[j]; }
    swp[t] = sum;
    __syncthreads();
    for (int off = 1; off < 256; off <<= 1) {
        int mine = swp[t];
        int add = (t >= off) ? swp[t - off] : 0;
        __syncthreads();
        swp[t] = mine + add;
        __syncthreads();
    }
    int run = swp[t] - sum;
#pragma unroll
    for (int j = 0; j < 4; ++j) {
        int b = 4 * t + j;
        lh[b] = run;
        lcur[b] = 0;
        if (v[j] > 0) lrun[b] = atomicAdd(&cursor[b], v[j]);
        run += v[j];
    }
    __syncthreads();
    for (int i = t; i < cnt; i += 256) {
        int d = dst[e0 + i];
        int s = src[e0 + i];
        int b = (unsigned)d >> BK_LOG;
        int lp = atomicAdd(&lcur[b], 1);
        int slot = lh[b] + lp;
        stg[slot] = ((unsigned)(d & (BK_NODES - 1)) << 17) | (unsigned)s;
        sbk[slot] = (unsigned short)b;
    }
    __syncthreads();
    for (int i = t; i < cnt; i += 256) {
        int b = sbk[i];
        int g = lrun[b] + (i - lh[b]);
        ebuf[g] = stg[i];
    }
}

// ---------------- stage 4: per-bucket CSR sort + row_ptr + dinv ------------
__global__ __launch_bounds__(256) void bucket_csr_kernel(
        unsigned int* __restrict__ ebuf, const int* __restrict__ bbase,
        float* __restrict__ dinv, int* __restrict__ row_ptr, int nN) {
    int b = blockIdx.x;
    int node_lo = b << BK_LOG;
    int nn = min(BK_NODES, nN - node_lo);
    int base = bbase[b];
    int cnt = bbase[b + 1] - base;
    if (cnt > BCAP) cnt = BCAP;
    __shared__ unsigned int in[BCAP];
    __shared__ unsigned int outb[BCAP];
    __shared__ int h[BK_NODES], sc[BK_NODES], lc[BK_NODES];
    int t = threadIdx.x;
    for (int i = t; i < cnt; i += 256) in[i] = ebuf[base + i];
    if (t < BK_NODES) { h[t] = 0; lc[t] = 0; }
    __syncthreads();
    for (int i = t; i < cnt; i += 256) atomicAdd(&h[in[i] >> 17], 1);
    __syncthreads();
    if (t < BK_NODES) sc[t] = h[t];
    __syncthreads();
    for (int off = 1; off < BK_NODES; off <<= 1) {
        int val = 0;
        if (t < BK_NODES) { val = sc[t]; if (t >= off) val += sc[t - off]; }
        __syncthreads();
        if (t < BK_NODES) sc[t] = val;
        __syncthreads();
    }
    if (t < BK_NODES && t < nn) {
        dinv[node_lo + t] = rsqrtf((float)h[t] + 1.0f);
        row_ptr[node_lo + t] = base + (sc[t] - h[t]);
    }
    __syncthreads();
    for (int i = t; i < cnt; i += 256) {
        unsigned int w = in[i];
        int dl = w >> 17;
        int lp = atomicAdd(&lc[dl], 1);
        outb[(sc[dl] - h[dl]) + lp] = w & 0x1FFFFu;
    }
    __syncthreads();
    for (int i = t; i < cnt; i += 256) ebuf[base + i] = outb[i];
}

// ---------------- pad + pre-scale helpers ----------------
// xp[node][c] = x[node][c] * dinv[node]  (pre-scaled for the gather)
__global__ void padx_kernel(const float* __restrict__ x, const float* __restrict__ dinv,
                            float* __restrict__ xp, int n) {
    int i = blockIdx.x * 256 + threadIdx.x;
    if (i < n * 32) {
        int node = i >> 5, c = i & 31;
        xp[i] = (c < IN_DIM) ? x[(size_t)node * IN_DIM + c] * dinv[node] : 0.f;
    }
}

__global__ void padw_kernel(const float* __restrict__ W1, float* __restrict__ W1p) {
    int i = blockIdx.x * 256 + threadIdx.x;
    if (i < 32 * HID) {
        int r = i >> 6, c = i & 63;
        W1p[i] = (r < IN_DIM) ? W1[r * HID + c] : 0.f;
    }
}

// ---------------- dense layer: out = in @ W [*dinv] [+bias,relu] -----------
template<int INF, int OUTF, bool ACT, bool SCALE>
__global__ __launch_bounds__(256) void gemm_kernel(
        const float* __restrict__ in, const float* __restrict__ W,
        const float* __restrict__ bias, const float* __restrict__ dinv,
        float* __restrict__ out, int n) {
    constexpr int TPN = OUTF / 4;
    constexpr int NPB = 256 / TPN;
    constexpr int LDK = INF + 4;
    __shared__ float sW[INF * OUTF];
    __shared__ float sIn[NPB][LDK];
    for (int i = threadIdx.x; i < INF * OUTF; i += 256) sW[i] = W[i];
    int node0 = blockIdx.x * NPB;
    for (int i = threadIdx.x; i < NPB * INF; i += 256) {
        int ln = i / INF, k = i % INF;
        int node = node0 + ln;
        sIn[ln][k] = (node < n) ? in[(size_t)node * INF + k] : 0.f;
    }
    __syncthreads();
    int g   = threadIdx.x / TPN;
    int of0 = (threadIdx.x % TPN) * 4;
    int node = node0 + g;
    float4 acc = make_float4(0.f, 0.f, 0.f, 0.f);
#pragma unroll
    for (int k = 0; k < INF; ++k) {
        float aj = sIn[g][k];
        const float4 wv = *(const float4*)&sW[k * OUTF + of0];
        acc.x += aj * wv.x; acc.y += aj * wv.y;
        acc.z += aj * wv.z; acc.w += aj * wv.w;
    }
    if (ACT) {
        const float4 bv = *(const float4*)&bias[of0];
        acc.x = fmaxf(acc.x + bv.x, 0.f);
        acc.y = fmaxf(acc.y + bv.y, 0.f);
        acc.z = fmaxf(acc.z + bv.z, 0.f);
        acc.w = fmaxf(acc.w + bv.w, 0.f);
    }
    if (node < n) {
        if (SCALE) {
            float s = dinv[node];
            acc.x *= s; acc.y *= s; acc.z *= s; acc.w *= s;
        }
        *(float4*)&out[(size_t)node * OUTF + of0] = acc;
    }
}

// ---------------- CSR gather on PRE-SCALED rows ----------------
// out[d] = act( dinv[d] * (hp[d] + sum_cols hp[c]) + bias )
// inner loop: col load -> hp load -> add. 16-deep, 4 accumulators.
template<int F, bool ACT>
__global__ __launch_bounds__(256) void gather_kernel(
        const float* __restrict__ hp, const float* __restrict__ dinv,
        const int* __restrict__ row_ptr, const int* __restrict__ col,
        const float* __restrict__ bias, float* __restrict__ agg, int n) {
    constexpr int NPW = 64 / F;
    int wid  = (blockIdx.x * 256 + threadIdx.x) >> 6;
    int lane = threadIdx.x & 63;
    int sub  = lane / F;
    int f    = lane % F;
    int node = wid * NPW + sub;
    if (node >= n) return;
    float a0 = hp[(size_t)node * F + f];   // self loop (pre-scaled)
    float a1 = 0.f, a2 = 0.f, a3 = 0.f;
    int e = row_ptr[node], end = row_ptr[node + 1];
    for (; e + 16 <= end; e += 16) {
        int c[16];
#pragma unroll
        for (int j = 0; j < 16; ++j) c[j] = ld_nt_i32(&col[e + j]);
        float v[16];
#pragma unroll
        for (int j = 0; j < 16; ++j) v[j] = hp[(size_t)c[j] * F + f];
#pragma unroll
        for (int j = 0; j < 4; ++j) {
            a0 += v[4 * j];     a1 += v[4 * j + 1];
            a2 += v[4 * j + 2]; a3 += v[4 * j + 3];
        }
    }
    for (; e + 4 <= end; e += 4) {
        int c0 = ld_nt_i32(&col[e]),     c1 = ld_nt_i32(&col[e + 1]);
        int c2 = ld_nt_i32(&col[e + 2]), c3 = ld_nt_i32(&col[e + 3]);
        a0 += hp[(size_t)c0 * F + f]; a1 += hp[(size_t)c1 * F + f];
        a2 += hp[(size_t)c2 * F + f]; a3 += hp[(size_t)c3 * F + f];
    }
    for (; e < end; ++e) a0 += hp[(size_t)ld_nt_i32(&col[e]) * F + f];
    float acc = ((a0 + a1) + (a2 + a3)) * dinv[node];
    float r = ACT ? fmaxf(acc + bias[f], 0.f) : acc;
    agg[(size_t)node * F + f] = r;
}

// ---------------- mean pool ----------------
__global__ __launch_bounds__(256) void pool_kernel(
        const float* __restrict__ h3, const int* __restrict__ batch,
        int n, float* __restrict__ pool) {
    int g = blockIdx.x;
    int lo = 0, hi = n;
    while (lo < hi) { int m = (lo + hi) >> 1; if (batch[m] < g) lo = m + 1; else hi = m; }
    int s = lo;
    hi = n;
    while (lo < hi) { int m = (lo + hi) >> 1; if (batch[m] < g + 1) lo = m + 1; else hi = m; }
    int e = lo;
    constexpr int F = OUT3;
    int ln = threadIdx.x / F;
    int f  = threadIdx.x % F;
    float acc = 0.f;
    for (int i = s + ln; i < e; i += 8)
        acc += h3[(size_t)i * F + f];
    __shared__ float red[8][F];
    red[ln][f] = acc;
    __syncthreads();
    if (ln == 0) {
        float t = 0.f;
#pragma unroll
        for (int j = 0; j < 8; ++j) t += red[j][f];
        float cnt = (float)((e - s) > 0 ? (e - s) : 1);
        pool[g * F + f] = t / cnt;
    }
}

// ---------------- head ----------------
__global__ __launch_bounds__(256) void head_kernel(
        const float* __restrict__ pool, const float* __restrict__ Wh1,
        const float* __restrict__ bh1, const float* __restrict__ Wh2,
        const float* __restrict__ bh2, float* __restrict__ out) {
    __shared__ float sW1[32 * 32];
    __shared__ float sb1[32];
    __shared__ float sW2[32];
    int t = threadIdx.x;
    for (int i = t; i < 1024; i += 256) sW1[i] = Wh1[i];
    if (t < 32) { sb1[t] = bh1[t]; sW2[t] = Wh2[t]; }
    __syncthreads();
    int g = t;
    float y = bh2[0];
    const float* p = &pool[g * 32];
#pragma unroll 4
    for (int j = 0; j < 32; ++j) {
        float a = sb1[j];
#pragma unroll
        for (int k = 0; k < 32; ++k) a += p[k] * sW1[k * 32 + j];
        y += fmaxf(a, 0.f) * sW2[j];
    }
    out[g] = y;
}

extern "C" void kernel_launch(void* const* d_in, const int* in_sizes, int n_in,
                              void* d_out, int out_size, void* d_ws, size_t ws_size,
                              hipStream_t stream) {
    const float* x    = (const float*)d_in[0];
    const int*   ei   = (const int*)  d_in[1];
    const int*   batch= (const int*)  d_in[2];
    const float* W1   = (const float*)d_in[3];
    const float* b1   = (const float*)d_in[4];
    const float* W2   = (const float*)d_in[5];
    const float* b2   = (const float*)d_in[6];
    const float* W3   = (const float*)d_in[7];
    const float* b3   = (const float*)d_in[8];
    const float* Wh1  = (const float*)d_in[9];
    const float* bh1  = (const float*)d_in[10];
    const float* Wh2  = (const float*)d_in[11];
    const float* bh2  = (const float*)d_in[12];
    float* out = (float*)d_out;

    const int N = in_sizes[0] / IN_DIM;
    const int E = in_sizes[1] / 2;
    const int* src = ei;
    const int* dst = ei + E;
    const int NB = (N + BK_NODES - 1) >> BK_LOG;

    // workspace layout (all 4B elements)
    char* base = (char*)d_ws;
    unsigned int* ebuf = (unsigned int*)base;       base += (size_t)E * 4;
    int*   bhist   = (int*)base;                    base += (size_t)MAXB * 4;
    int*   bbase   = (int*)base;                    base += (size_t)(MAXB + 1) * 4;
    int*   cursor  = (int*)base;                    base += (size_t)MAXB * 4;
    int*   row_ptr = (int*)base;                    base += (size_t)(N + 1) * 4;
    float* dinv    = (float*)base;                  base += (size_t)N * 4;
    float* W1p     = (float*)base;                  base += (size_t)32 * HID * 4;
    float* bufA    = (float*)base;                  base += (size_t)N * HID * 4;
    float* bufB    = (float*)base;                  base += (size_t)N * HID * 4;
    float* pool    = (float*)base;

    // ---- CSR build (coalesced counting sort) ----
    hipMemsetAsync(bhist, 0, (size_t)MAXB * sizeof(int), stream);
    bucket_hist<<<(E + 8191) / 8192, 256, 0, stream>>>(dst, bhist, E);
    bucket_scan<<<1, 256, 0, stream>>>(bhist, bbase, cursor, row_ptr, NB, E, N);
    partition_kernel<<<(E + EPB1 - 1) / EPB1, 256, 0, stream>>>(src, dst, cursor, ebuf, E);
    bucket_csr_kernel<<<NB, 256, 0, stream>>>(ebuf, bbase, dinv, row_ptr, N);
    const int* col = (const int*)ebuf;

    // ---- layer 1 (reordered): aggX = A_hat Xp' ; h1 = relu(aggX @ W1p + b1)
    padx_kernel<<<((size_t)N * 32 + 255) / 256, 256, 0, stream>>>(x, dinv, bufB, N);
    padw_kernel<<<(32 * HID + 255) / 256, 256, 0, stream>>>(W1, W1p);
    gather_kernel<32, false><<<(N + 7) / 8, 256, 0, stream>>>(bufB, dinv, row_ptr, col, nullptr, bufA, N);
    gemm_kernel<32, HID, true, false><<<(N + 15) / 16, 256, 0, stream>>>(bufA, W1p, b1, nullptr, bufB, N);

    // ---- layer 2: t2' = (h1 @ W2)*dinv ; h2 = relu(dinv*(sum t2') + b2) ----
    gemm_kernel<HID, HID, false, true><<<(N + 15) / 16, 256, 0, stream>>>(bufB, W2, nullptr, dinv, bufA, N);
    gather_kernel<HID, true><<<(N + 3) / 4, 256, 0, stream>>>(bufA, dinv, row_ptr, col, b2, bufB, N);

    // ---- layer 3: t3' = (h2 @ W3)*dinv ; h3 = relu(dinv*(sum t3') + b3) ----
    gemm_kernel<HID, OUT3, false, true><<<(N + 31) / 32, 256, 0, stream>>>(bufB, W3, nullptr, dinv, bufA, N);
    gather_kernel<OUT3, true><<<(N + 7) / 8, 256, 0, stream>>>(bufA, dinv, row_ptr, col, b3, bufB, N);

    // ---- pool + head ----
    pool_kernel<<<256, 256, 0, stream>>>(bufB, batch, N, pool);
    head_kernel<<<1, 256, 0, stream>>>(pool, Wh1, bh1, Wh2, bh2, out);
}